// Round 1
// baseline (252.301 us; speedup 1.0000x reference)
//
#include <hip/hip_runtime.h>
#include <math.h>

#define NB 8
#define NC 256
#define ND 32
#define NN 4096
#define NM 320                 // fused rows: 32 q + 32 k + 256 v
#define LOG2E 1.44269504088896f
#define XSTR 264               // proj LDS row stride (shorts), 16B-aligned rows

typedef short short8 __attribute__((ext_vector_type(8)));
typedef float f32x4 __attribute__((ext_vector_type(4)));

// LDS-only barrier: drains ds ops, leaves global loads in flight (vmcnt
// untouched) — compiler inserts fine-grained vmcnt(N) at first use.
#define LDS_BARRIER() asm volatile("s_waitcnt lgkmcnt(0)\ns_barrier" ::: "memory")

__device__ __forceinline__ unsigned int f2bf_u(float f) {
    return (__float_as_uint(f) + 0x8000u) >> 16;
}
__device__ __forceinline__ unsigned short f2bf(float f) {
    return (unsigned short)f2bf_u(f);
}

// ---------------------------------------------------------------------------
// Repack fused weights [320x256] -> bf16 fragments.  Rows 0..31 = Wq*LOG2E,
// 32..63 = Wk, 64..319 = Wv.  Also bias[320].
// ---------------------------------------------------------------------------
__global__ __launch_bounds__(256) void repack_kernel(
    const float* __restrict__ Wq, const float* __restrict__ bq,
    const float* __restrict__ Wk, const float* __restrict__ bk,
    const float* __restrict__ Wv, const float* __restrict__ bv,
    unsigned short* __restrict__ wp, float* __restrict__ bias)
{
    const int T    = blockIdx.x * 256 + threadIdx.x;   // 81920 threads
    const int j    = T & 7;
    const int lane = (T >> 3) & 63;
    const int ks   = (T >> 9) & 7;
    const int mt   = T >> 12;
    const int m = mt * 16 + (lane & 15);
    const int k = ks * 32 + ((lane >> 4) << 3) + j;
    float wv;
    if (m < 32)       wv = Wq[m * NC + k] * LOG2E;
    else if (m < 64)  wv = Wk[(m - 32) * NC + k];
    else              wv = Wv[(m - 64) * NC + k];
    wp[T] = f2bf(wv);
    if (T < NM) {
        float bb;
        if (T < 32)      bb = bq[T] * LOG2E;
        else if (T < 64) bb = bk[T - 32];
        else             bb = bv[T - 64];
        bias[T] = bb;
    }
}

// ---------------------------------------------------------------------------
// MFMA projection (unchanged): A = x (m = pixel), B = W^T.
// ---------------------------------------------------------------------------
__global__ __launch_bounds__(256, 4) void proj_kernel(
    const float* __restrict__ x,
    const unsigned short* __restrict__ wp,
    const float* __restrict__ bias,
    unsigned short* __restrict__ q_ws,
    unsigned short* __restrict__ k_ws,
    unsigned short* __restrict__ v_ws)
{
    __shared__ __align__(16) unsigned short xs[32 * XSTR];   // 16.9 KB

    const int b  = blockIdx.x >> 7;          // 128 tiles per batch
    const int n0 = (blockIdx.x & 127) << 5;
    const int t  = threadIdx.x;

    {
        const int n  = t & 31;
        const int cg = t >> 5;               // 0..7
        const float* xb = x + (size_t)b * NC * NN + n0 + n;
        #pragma unroll
        for (int it = 0; it < 8; ++it) {
            const int c = 32 * it + 4 * cg;
            const float x0 = xb[(size_t)(c + 0) * NN];
            const float x1 = xb[(size_t)(c + 1) * NN];
            const float x2 = xb[(size_t)(c + 2) * NN];
            const float x3 = xb[(size_t)(c + 3) * NN];
            uint2 pk;
            pk.x = (f2bf_u(x1) << 16) | f2bf_u(x0);
            pk.y = (f2bf_u(x3) << 16) | f2bf_u(x2);
            *(uint2*)(xs + n * XSTR + c) = pk;
        }
    }
    __syncthreads();

    const int w    = t >> 6;
    const int lane = t & 63;
    const int li = lane & 15;
    const int qd = lane >> 4;

    f32x4 acc[5][2];
    #pragma unroll
    for (int u = 0; u < 5; ++u) {
        const float bb = bias[(w + 4 * u) * 16 + li];
        acc[u][0] = (f32x4){bb, bb, bb, bb};
        acc[u][1] = (f32x4){bb, bb, bb, bb};
    }

    #pragma unroll
    for (int ks = 0; ks < 8; ++ks) {
        short8 af[2];
        #pragma unroll
        for (int mt = 0; mt < 2; ++mt)
            af[mt] = *(const short8*)(xs + (mt * 16 + li) * XSTR + ks * 32 + qd * 8);
        #pragma unroll
        for (int u = 0; u < 5; ++u) {
            const int ct = w + 4 * u;
            const short8 bf = *(const short8*)(wp + (size_t)((ct * 8 + ks) * 64 + lane) * 8);
            acc[u][0] = __builtin_amdgcn_mfma_f32_16x16x32_bf16(af[0], bf, acc[u][0], 0, 0, 0);
            acc[u][1] = __builtin_amdgcn_mfma_f32_16x16x32_bf16(af[1], bf, acc[u][1], 0, 0, 0);
        }
    }

    #pragma unroll
    for (int u = 0; u < 5; ++u) {
        const int ct = w + 4 * u;
        if (ct < 4) {
            unsigned short* dst = (ct < 2) ? q_ws : k_ws;
            const int d = (ct & 1) * 16 + li;
            #pragma unroll
            for (int mt = 0; mt < 2; ++mt)
                #pragma unroll
                for (int r = 0; r < 4; ++r) {
                    const int n = n0 + mt * 16 + 4 * qd + r;
                    dst[((size_t)b * NN + n) * ND + d] = f2bf(acc[u][mt][r]);
                }
        } else {
            const int cv = (ct - 4) * 16 + li;
            #pragma unroll
            for (int mt = 0; mt < 2; ++mt) {
                const int n = n0 + mt * 16 + 4 * qd;
                uint2 pk;
                pk.x = (f2bf_u(acc[u][mt][1]) << 16) | f2bf_u(acc[u][mt][0]);
                pk.y = (f2bf_u(acc[u][mt][3]) << 16) | f2bf_u(acc[u][mt][2]);
                *(uint2*)(v_ws + ((size_t)b * NC + cv) * NN + n) = pk;
            }
        }
    }
}

// ---------------------------------------------------------------------------
// Flash attention, deep-pipelined.  R8: 4-wave blocks (256 thr), i-tile 64,
// 64 channels per wave; grid = 512 (2 blocks/CU, 8 waves/CU).
// Wave w: S-duty strip sw=w (16 i rows x full 64 j: 4 S-MFMA + 16 exp2);
// PV-duty 64 channels c0=64w (32 PV-MFMA/chunk).
// vs R7 (8 waves, 32 ch/wave): halves the per-CU LDS read burst per chunk
// (each wave amortizes its full-P read over 2x the MFMAs), shrinks barrier
// groups 8->4 waves, and doubles per-wave accumulator ILP.
// DOS is issued BEFORE DOPV each interval so the P-writes sit at the FRONT
// of the LDS queue — their completion overlaps the read burst instead of
// being the tail the final lgkmcnt(0) drain waits on.  Global loads stay in
// flight across barriers (vmcnt(N) waits at first use, AITER-style).
// ---------------------------------------------------------------------------
__global__ __launch_bounds__(256, 2) void attn_kernel(
    const unsigned short* __restrict__ q_ws,
    const unsigned short* __restrict__ k_ws,
    const unsigned short* __restrict__ v_ws,
    float* __restrict__ out)
{
    __shared__ __align__(16) unsigned short Pb[2][4][16 * 72];  // 18.4 KB
    __shared__ float lred[4][16];

    const int b  = blockIdx.x & 7;           // batch == XCD
    const int i0 = (blockIdx.x >> 3) * 64;
    const int w    = threadIdx.x >> 6;       // 0..3
    const int lane = threadIdx.x & 63;
    const int li = lane & 15;
    const int qd = lane >> 4;
    const int sw = w;                        // S strip duty (16 i rows)
    const int c0 = 64 * w;                   // PV channel slice (64 ch)

    const short8 qf = *(const short8*)(q_ws + ((size_t)b * NN + i0 + 16 * sw + li) * ND + qd * 8);
    const unsigned short* kb = k_ws + ((size_t)b * NN + li) * ND + qd * 8;
    const unsigned short* vb = v_ws + ((size_t)b * NC + c0 + li) * NN + qd * 8;

    unsigned short* PA = &Pb[0][0][0];       // even chunks
    unsigned short* PB = &Pb[1][0][0];       // odd chunks

    f32x4 o[4][4];
    #pragma unroll
    for (int sb = 0; sb < 4; ++sb)
        #pragma unroll
        for (int ct = 0; ct < 4; ++ct)
            o[sb][ct] = (f32x4){0.f, 0.f, 0.f, 0.f};
    float l_loc = 0.f;
    const f32x4 z4 = {0.f, 0.f, 0.f, 0.f};

    short8 kA[4], kB[4], vA[4][2], vB[4][2];

    auto LKF = [&](int j0, short8 (&kf)[4]) {
        #pragma unroll
        for (int tt = 0; tt < 4; ++tt)
            kf[tt] = *(const short8*)(kb + (size_t)(j0 + 16 * tt) * ND);
    };
    auto LVF = [&](int j0, short8 (&vf)[4][2]) {
        #pragma unroll
        for (int t = 0; t < 4; ++t) {
            const unsigned short* vt = vb + (size_t)(16 * t) * NN;
            vf[t][0] = *(const short8*)(vt + j0);
            vf[t][1] = *(const short8*)(vt + j0 + 32);
        }
    };
    // S for strip sw, all 64 j of the chunk: s[r] has i = li (col),
    // j = 16*tt + 4*qd + r (row); P[strip][i=li][j].
    auto DOS = [&](short8 (&kf)[4], unsigned short* P) {
        unsigned short* Pw = P + sw * (16 * 72) + li * 72 + 4 * qd;
        #pragma unroll
        for (int tt = 0; tt < 4; ++tt) {
            const f32x4 s = __builtin_amdgcn_mfma_f32_16x16x32_bf16(kf[tt], qf, z4, 0, 0, 0);
            const float p0 = __builtin_amdgcn_exp2f(s[0]);
            const float p1 = __builtin_amdgcn_exp2f(s[1]);
            const float p2 = __builtin_amdgcn_exp2f(s[2]);
            const float p3 = __builtin_amdgcn_exp2f(s[3]);
            l_loc += (p0 + p1) + (p2 + p3);
            const unsigned u0 = __float_as_uint(p0) + 0x8000u;
            const unsigned u1 = __float_as_uint(p1) + 0x8000u;
            const unsigned u2 = __float_as_uint(p2) + 0x8000u;
            const unsigned u3 = __float_as_uint(p3) + 0x8000u;
            uint2 pk;
            pk.x = __builtin_amdgcn_perm(u1, u0, 0x07060302u);
            pk.y = __builtin_amdgcn_perm(u3, u2, 0x07060302u);
            *(uint2*)(Pw + 16 * tt) = pk;
        }
    };
    auto DOPV = [&](const unsigned short* P, short8 (&vf)[4][2]) {
        #pragma unroll
        for (int sb = 0; sb < 4; ++sb) {
            const unsigned short* Pr = P + sb * (16 * 72) + li * 72 + qd * 8;
            const short8 pf0 = *(const short8*)(Pr);
            const short8 pf1 = *(const short8*)(Pr + 32);
            #pragma unroll
            for (int ct = 0; ct < 4; ++ct) {
                o[sb][ct] = __builtin_amdgcn_mfma_f32_16x16x32_bf16(vf[ct][0], pf0, o[sb][ct], 0, 0, 0);
                o[sb][ct] = __builtin_amdgcn_mfma_f32_16x16x32_bf16(vf[ct][1], pf1, o[sb][ct], 0, 0, 0);
            }
        }
    };

    // ---- prologue: chunk 0 S exposed once; kf(1) prefetched ----
    LKF(0, kA); LVF(0, vA);
    DOS(kA, PA);
    LKF(64, kB);
    LDS_BARRIER();

    // ---- main loop: 31 double-intervals (chunks 0..61 PV, 1..62 S) ----
    int j = 0;
    #pragma unroll 1
    for (int it = 0; it < 31; ++it) {
        // interval n=2it (even): S(n+1) | PV(n) | prefetch v(n+1), k(n+2)
        LVF(j + 64, vB);
        DOS(kB, PB);
        DOPV(PA, vA);
        LKF(j + 128, kA);
        LDS_BARRIER();
        // interval n=2it+1 (odd)
        LVF(j + 128, vA);
        DOS(kA, PA);
        DOPV(PB, vB);
        LKF(j + 192, kB);
        LDS_BARRIER();
        j += 128;
    }
    // j = 3968: interval 62 (even): S(63) | PV(62)
    LVF(4032, vB);
    DOS(kB, PB);
    DOPV(PA, vA);
    LDS_BARRIER();
    DOPV(PB, vB);    // chunk 63

    // ---- l reduction: each wave covered full j for its strip; qd via shfl ----
    l_loc += __shfl_xor(l_loc, 16, 64);
    l_loc += __shfl_xor(l_loc, 32, 64);
    if (lane < 16) lred[w][li] = l_loc;
    __syncthreads();
    float linv[4];
    #pragma unroll
    for (int sb = 0; sb < 4; ++sb)
        linv[sb] = 1.0f / lred[sb][li];

    #pragma unroll
    for (int sb = 0; sb < 4; ++sb)
        #pragma unroll
        for (int ct = 0; ct < 4; ++ct) {
            const int c = c0 + ct * 16 + qd * 4;
            float* op = out + ((size_t)b * NC + c) * NN + i0 + 16 * sb + li;
            #pragma unroll
            for (int r = 0; r < 4; ++r)
                op[(size_t)r * NN] = o[sb][ct][r] * linv[sb];
        }
}

// ---------------------------------------------------------------------------
extern "C" void kernel_launch(void* const* d_in, const int* in_sizes, int n_in,
                              void* d_out, int out_size, void* d_ws, size_t ws_size,
                              hipStream_t stream) {
    const float* x  = (const float*)d_in[0];
    const float* Wq = (const float*)d_in[1];
    const float* bq = (const float*)d_in[2];
    const float* Wk = (const float*)d_in[3];
    const float* bk = (const float*)d_in[4];
    const float* Wv = (const float*)d_in[5];
    const float* bv = (const float*)d_in[6];
    float* out = (float*)d_out;

    unsigned short* q_ws = (unsigned short*)d_ws;            // 2 MB
    unsigned short* k_ws = q_ws + (size_t)NB * NN * ND;      // 2 MB
    unsigned short* v_ws = k_ws + (size_t)NB * NN * ND;      // 16 MB
    unsigned short* wp   = v_ws + (size_t)NB * NC * NN;      // 160 KB
    float*          bias = (float*)(wp + (size_t)NM * NC);   // 1.25 KB

    repack_kernel<<<NM * NC / 256, 256, 0, stream>>>(Wq, bq, Wk, bk, Wv, bv, wp, bias);
    proj_kernel<<<NB * (NN / 32), 256, 0, stream>>>(x, wp, bias, q_ws, k_ws, v_ws);
    attn_kernel<<<NB * (NN / 64), 256, 0, stream>>>(q_ws, k_ws, v_ws, out);
}

// Round 2
// 247.449 us; speedup vs baseline: 1.0196x; 1.0196x over previous
//
#include <hip/hip_runtime.h>
#include <math.h>

#define NB 8
#define NC 256
#define ND 32
#define NN 4096
#define NM 320                 // fused rows: 32 q + 32 k + 256 v
#define LOG2E 1.44269504088896f
#define XSTR 264               // proj LDS row stride (shorts), 16B-aligned rows

typedef short short8 __attribute__((ext_vector_type(8)));
typedef float f32x4 __attribute__((ext_vector_type(4)));

// LDS-only barrier: drains ds ops, leaves global loads in flight (vmcnt
// untouched) — compiler inserts fine-grained vmcnt(N) at first use.
#define LDS_BARRIER() asm volatile("s_waitcnt lgkmcnt(0)\ns_barrier" ::: "memory")

__device__ __forceinline__ unsigned int f2bf_u(float f) {
    return (__float_as_uint(f) + 0x8000u) >> 16;
}
__device__ __forceinline__ unsigned short f2bf(float f) {
    return (unsigned short)f2bf_u(f);
}

// ---------------------------------------------------------------------------
// Repack fused weights [320x256] -> bf16 fragments.  Rows 0..31 = Wq*LOG2E,
// 32..63 = Wk, 64..319 = Wv.  Also bias[320].
// ---------------------------------------------------------------------------
__global__ __launch_bounds__(256) void repack_kernel(
    const float* __restrict__ Wq, const float* __restrict__ bq,
    const float* __restrict__ Wk, const float* __restrict__ bk,
    const float* __restrict__ Wv, const float* __restrict__ bv,
    unsigned short* __restrict__ wp, float* __restrict__ bias)
{
    const int T    = blockIdx.x * 256 + threadIdx.x;   // 81920 threads
    const int j    = T & 7;
    const int lane = (T >> 3) & 63;
    const int ks   = (T >> 9) & 7;
    const int mt   = T >> 12;
    const int m = mt * 16 + (lane & 15);
    const int k = ks * 32 + ((lane >> 4) << 3) + j;
    float wv;
    if (m < 32)       wv = Wq[m * NC + k] * LOG2E;
    else if (m < 64)  wv = Wk[(m - 32) * NC + k];
    else              wv = Wv[(m - 64) * NC + k];
    wp[T] = f2bf(wv);
    if (T < NM) {
        float bb;
        if (T < 32)      bb = bq[T] * LOG2E;
        else if (T < 64) bb = bk[T - 32];
        else             bb = bv[T - 64];
        bias[T] = bb;
    }
}

// ---------------------------------------------------------------------------
// MFMA projection (unchanged): A = x (m = pixel), B = W^T.
// ---------------------------------------------------------------------------
__global__ __launch_bounds__(256, 4) void proj_kernel(
    const float* __restrict__ x,
    const unsigned short* __restrict__ wp,
    const float* __restrict__ bias,
    unsigned short* __restrict__ q_ws,
    unsigned short* __restrict__ k_ws,
    unsigned short* __restrict__ v_ws)
{
    __shared__ __align__(16) unsigned short xs[32 * XSTR];   // 16.9 KB

    const int b  = blockIdx.x >> 7;          // 128 tiles per batch
    const int n0 = (blockIdx.x & 127) << 5;
    const int t  = threadIdx.x;

    {
        const int n  = t & 31;
        const int cg = t >> 5;               // 0..7
        const float* xb = x + (size_t)b * NC * NN + n0 + n;
        #pragma unroll
        for (int it = 0; it < 8; ++it) {
            const int c = 32 * it + 4 * cg;
            const float x0 = xb[(size_t)(c + 0) * NN];
            const float x1 = xb[(size_t)(c + 1) * NN];
            const float x2 = xb[(size_t)(c + 2) * NN];
            const float x3 = xb[(size_t)(c + 3) * NN];
            uint2 pk;
            pk.x = (f2bf_u(x1) << 16) | f2bf_u(x0);
            pk.y = (f2bf_u(x3) << 16) | f2bf_u(x2);
            *(uint2*)(xs + n * XSTR + c) = pk;
        }
    }
    __syncthreads();

    const int w    = t >> 6;
    const int lane = t & 63;
    const int li = lane & 15;
    const int qd = lane >> 4;

    f32x4 acc[5][2];
    #pragma unroll
    for (int u = 0; u < 5; ++u) {
        const float bb = bias[(w + 4 * u) * 16 + li];
        acc[u][0] = (f32x4){bb, bb, bb, bb};
        acc[u][1] = (f32x4){bb, bb, bb, bb};
    }

    #pragma unroll
    for (int ks = 0; ks < 8; ++ks) {
        short8 af[2];
        #pragma unroll
        for (int mt = 0; mt < 2; ++mt)
            af[mt] = *(const short8*)(xs + (mt * 16 + li) * XSTR + ks * 32 + qd * 8);
        #pragma unroll
        for (int u = 0; u < 5; ++u) {
            const int ct = w + 4 * u;
            const short8 bf = *(const short8*)(wp + (size_t)((ct * 8 + ks) * 64 + lane) * 8);
            acc[u][0] = __builtin_amdgcn_mfma_f32_16x16x32_bf16(af[0], bf, acc[u][0], 0, 0, 0);
            acc[u][1] = __builtin_amdgcn_mfma_f32_16x16x32_bf16(af[1], bf, acc[u][1], 0, 0, 0);
        }
    }

    #pragma unroll
    for (int u = 0; u < 5; ++u) {
        const int ct = w + 4 * u;
        if (ct < 4) {
            unsigned short* dst = (ct < 2) ? q_ws : k_ws;
            const int d = (ct & 1) * 16 + li;
            #pragma unroll
            for (int mt = 0; mt < 2; ++mt)
                #pragma unroll
                for (int r = 0; r < 4; ++r) {
                    const int n = n0 + mt * 16 + 4 * qd + r;
                    dst[((size_t)b * NN + n) * ND + d] = f2bf(acc[u][mt][r]);
                }
        } else {
            const int cv = (ct - 4) * 16 + li;
            #pragma unroll
            for (int mt = 0; mt < 2; ++mt) {
                const int n = n0 + mt * 16 + 4 * qd;
                uint2 pk;
                pk.x = (f2bf_u(acc[u][mt][1]) << 16) | f2bf_u(acc[u][mt][0]);
                pk.y = (f2bf_u(acc[u][mt][3]) << 16) | f2bf_u(acc[u][mt][2]);
                *(uint2*)(v_ws + ((size_t)b * NC + cv) * NN + n) = pk;
            }
        }
    }
}

// ---------------------------------------------------------------------------
// Flash attention, deep-pipelined.  R9: 4-wave blocks (256 thr), i-tile 64,
// 64 channels per wave; grid = 512 (2 blocks/CU, 8 waves/CU).
// Wave w: S-duty strip sw=w (16 i rows x full 64 j), PV-duty 64 ch c0=64w.
//
// R8 lesson: per-interval time (~6100 cyc) was invariant to LDS traffic,
// barrier-group size and per-wave ILP -> the floor is the per-interval
// barrier itself (drain + turnaround + wave re-lockstep), paid 64x.
// R9: FOUR P buffers, S computed TWO chunks ahead (DOS(n+2) in interval n),
// barrier only after every ODD interval (32 barriers instead of 64).
// Correctness: P[c] written at interval c-2, read at interval c -> a barrier
// always separates writer and reader (end of c-1 for even c, end of c-2 for
// odd c); buffer WAR similarly separated; wave skew bounded <2 intervals by
// the every-other barrier, and in-flight buffers {n..n+3} mod 4 are distinct.
// Global loads stay in flight across barriers (vmcnt(N) at first use).
// ---------------------------------------------------------------------------
__global__ __launch_bounds__(256, 2) void attn_kernel(
    const unsigned short* __restrict__ q_ws,
    const unsigned short* __restrict__ k_ws,
    const unsigned short* __restrict__ v_ws,
    float* __restrict__ out)
{
    __shared__ __align__(16) unsigned short Pb[4][4][16 * 72];  // 36.9 KB
    __shared__ float lred[4][16];

    const int b  = blockIdx.x & 7;           // batch == XCD
    const int i0 = (blockIdx.x >> 3) * 64;
    const int w    = threadIdx.x >> 6;       // 0..3
    const int lane = threadIdx.x & 63;
    const int li = lane & 15;
    const int qd = lane >> 4;
    const int sw = w;                        // S strip duty (16 i rows)
    const int c0 = 64 * w;                   // PV channel slice (64 ch)

    const short8 qf = *(const short8*)(q_ws + ((size_t)b * NN + i0 + 16 * sw + li) * ND + qd * 8);
    const unsigned short* kb = k_ws + ((size_t)b * NN + li) * ND + qd * 8;
    const unsigned short* vb = v_ws + ((size_t)b * NC + c0 + li) * NN + qd * 8;

    unsigned short* Pq0 = &Pb[0][0][0];
    unsigned short* Pq1 = &Pb[1][0][0];
    unsigned short* Pq2 = &Pb[2][0][0];
    unsigned short* Pq3 = &Pb[3][0][0];

    f32x4 o[4][4];
    #pragma unroll
    for (int sb = 0; sb < 4; ++sb)
        #pragma unroll
        for (int ct = 0; ct < 4; ++ct)
            o[sb][ct] = (f32x4){0.f, 0.f, 0.f, 0.f};
    float l_loc = 0.f;
    const f32x4 z4 = {0.f, 0.f, 0.f, 0.f};

    short8 kA[4], kB[4], vA[4][2], vB[4][2];

    auto LKF = [&](int j0, short8 (&kf)[4]) {
        #pragma unroll
        for (int tt = 0; tt < 4; ++tt)
            kf[tt] = *(const short8*)(kb + (size_t)(j0 + 16 * tt) * ND);
    };
    auto LVF = [&](int j0, short8 (&vf)[4][2]) {
        #pragma unroll
        for (int t = 0; t < 4; ++t) {
            const unsigned short* vt = vb + (size_t)(16 * t) * NN;
            vf[t][0] = *(const short8*)(vt + j0);
            vf[t][1] = *(const short8*)(vt + j0 + 32);
        }
    };
    // S for strip sw, all 64 j of the chunk: s[r] has i = li (col),
    // j = 16*tt + 4*qd + r (row); P[strip][i=li][j].
    auto DOS = [&](short8 (&kf)[4], unsigned short* P) {
        unsigned short* Pw = P + sw * (16 * 72) + li * 72 + 4 * qd;
        #pragma unroll
        for (int tt = 0; tt < 4; ++tt) {
            const f32x4 s = __builtin_amdgcn_mfma_f32_16x16x32_bf16(kf[tt], qf, z4, 0, 0, 0);
            const float p0 = __builtin_amdgcn_exp2f(s[0]);
            const float p1 = __builtin_amdgcn_exp2f(s[1]);
            const float p2 = __builtin_amdgcn_exp2f(s[2]);
            const float p3 = __builtin_amdgcn_exp2f(s[3]);
            l_loc += (p0 + p1) + (p2 + p3);
            const unsigned u0 = __float_as_uint(p0) + 0x8000u;
            const unsigned u1 = __float_as_uint(p1) + 0x8000u;
            const unsigned u2 = __float_as_uint(p2) + 0x8000u;
            const unsigned u3 = __float_as_uint(p3) + 0x8000u;
            uint2 pk;
            pk.x = __builtin_amdgcn_perm(u1, u0, 0x07060302u);
            pk.y = __builtin_amdgcn_perm(u3, u2, 0x07060302u);
            *(uint2*)(Pw + 16 * tt) = pk;
        }
    };
    auto DOPV = [&](const unsigned short* P, short8 (&vf)[4][2]) {
        #pragma unroll
        for (int sb = 0; sb < 4; ++sb) {
            const unsigned short* Pr = P + sb * (16 * 72) + li * 72 + qd * 8;
            const short8 pf0 = *(const short8*)(Pr);
            const short8 pf1 = *(const short8*)(Pr + 32);
            #pragma unroll
            for (int ct = 0; ct < 4; ++ct) {
                o[sb][ct] = __builtin_amdgcn_mfma_f32_16x16x32_bf16(vf[ct][0], pf0, o[sb][ct], 0, 0, 0);
                o[sb][ct] = __builtin_amdgcn_mfma_f32_16x16x32_bf16(vf[ct][1], pf1, o[sb][ct], 0, 0, 0);
            }
        }
    };

    // ---- prologue: S(0), S(1) exposed once; k(2) prefetched; V(0) loaded ----
    LKF(0, kA); LKF(64, kB); LVF(0, vA);
    DOS(kA, Pq0);
    DOS(kB, Pq1);
    LKF(128, kA);
    LDS_BARRIER();

    // ---- main loop: 15 superblocks of 4 intervals; barrier every 2nd ----
    // Interval n: LVF(n+1) | DOPV(n) | DOS(n+2) | LKF(n+3)
    int j = 0;
    #pragma unroll 1
    for (int it = 0; it < 15; ++it) {
        // interval 4t+0 (no barrier)
        LVF(j + 64, vB);
        DOPV(Pq0, vA);
        DOS(kA, Pq2);
        LKF(j + 192, kB);
        // interval 4t+1
        LVF(j + 128, vA);
        DOPV(Pq1, vB);
        DOS(kB, Pq3);
        LKF(j + 256, kA);
        LDS_BARRIER();
        // interval 4t+2 (no barrier)
        LVF(j + 192, vB);
        DOPV(Pq2, vA);
        DOS(kA, Pq0);
        LKF(j + 320, kB);
        // interval 4t+3
        LVF(j + 256, vA);
        DOPV(Pq3, vB);
        DOS(kB, Pq1);
        LKF(j + 384, kA);
        LDS_BARRIER();
        j += 256;
    }
    // j = 3840: interval 60 (no barrier)
    LVF(3904, vB);
    DOPV(Pq0, vA);
    DOS(kA, Pq2);
    LKF(4032, kB);
    // interval 61
    LVF(3968, vA);
    DOPV(Pq1, vB);
    DOS(kB, Pq3);
    LDS_BARRIER();
    // interval 62 (no barrier; P2/P3 written before the barrier above)
    LVF(4032, vB);
    DOPV(Pq2, vA);
    // interval 63
    DOPV(Pq3, vB);

    // ---- l reduction: each wave covered full j for its strip; qd via shfl ----
    l_loc += __shfl_xor(l_loc, 16, 64);
    l_loc += __shfl_xor(l_loc, 32, 64);
    if (lane < 16) lred[w][li] = l_loc;
    __syncthreads();
    float linv[4];
    #pragma unroll
    for (int sb = 0; sb < 4; ++sb)
        linv[sb] = 1.0f / lred[sb][li];

    #pragma unroll
    for (int sb = 0; sb < 4; ++sb)
        #pragma unroll
        for (int ct = 0; ct < 4; ++ct) {
            const int c = c0 + ct * 16 + qd * 4;
            float* op = out + ((size_t)b * NC + c) * NN + i0 + 16 * sb + li;
            #pragma unroll
            for (int r = 0; r < 4; ++r)
                op[(size_t)r * NN] = o[sb][ct][r] * linv[sb];
        }
}

// ---------------------------------------------------------------------------
extern "C" void kernel_launch(void* const* d_in, const int* in_sizes, int n_in,
                              void* d_out, int out_size, void* d_ws, size_t ws_size,
                              hipStream_t stream) {
    const float* x  = (const float*)d_in[0];
    const float* Wq = (const float*)d_in[1];
    const float* bq = (const float*)d_in[2];
    const float* Wk = (const float*)d_in[3];
    const float* bk = (const float*)d_in[4];
    const float* Wv = (const float*)d_in[5];
    const float* bv = (const float*)d_in[6];
    float* out = (float*)d_out;

    unsigned short* q_ws = (unsigned short*)d_ws;            // 2 MB
    unsigned short* k_ws = q_ws + (size_t)NB * NN * ND;      // 2 MB
    unsigned short* v_ws = k_ws + (size_t)NB * NN * ND;      // 16 MB
    unsigned short* wp   = v_ws + (size_t)NB * NC * NN;      // 160 KB
    float*          bias = (float*)(wp + (size_t)NM * NC);   // 1.25 KB

    repack_kernel<<<NM * NC / 256, 256, 0, stream>>>(Wq, bq, Wk, bk, Wv, bv, wp, bias);
    proj_kernel<<<NB * (NN / 32), 256, 0, stream>>>(x, wp, bias, q_ws, k_ws, v_ws);
    attn_kernel<<<NB * (NN / 64), 256, 0, stream>>>(q_ws, k_ws, v_ws, out);
}